// Round 5
// baseline (3163.881 us; speedup 1.0000x reference)
//
#include <hip/hip_runtime.h>
#include <cstdint>

#define N_NODES 100000
#define E_EDGES 1600000
#define D_IN 64
#define H_DIM 128
#define OUT_DIM 64
#define EPS_GEN 1e-7f
#define BN_EPS 1e-5f
#define NORM_EPS 1e-12f

#define AGG_REPS 6      // amplification factor for aggregate (idempotent)
#define PROBE_R 8       // amplification factor for hist/scatter probes

// Clang-native int vector: __builtin_nontemporal_load requires a real vector
// type (HIP's int4 is a class and is rejected).
typedef int ivec4 __attribute__((ext_vector_type(4)));

// ---------------------------------------------------------------------------
// CSR build, step 1: per-dst degree histogram. ivec4 = 4 edges/thread.
// ---------------------------------------------------------------------------
__global__ __launch_bounds__(256) void hist_kernel(
    const int* __restrict__ dst, int* __restrict__ counts)
{
    int t = blockIdx.x * 256 + threadIdx.x;
    if (t < E_EDGES / 4) {
        ivec4 d = __builtin_nontemporal_load((const ivec4*)dst + t);
        atomicAdd(&counts[d.x], 1);
        atomicAdd(&counts[d.y], 1);
        atomicAdd(&counts[d.z], 1);
        atomicAdd(&counts[d.w], 1);
    }
}

// ---------------------------------------------------------------------------
// CSR build, step 2a: per-block inclusive scan of counts (256/block).
// ---------------------------------------------------------------------------
__global__ __launch_bounds__(256) void scan1(
    const int* __restrict__ counts, int* __restrict__ row_start,
    int* __restrict__ bsum)
{
    __shared__ int s[256];
    int t = threadIdx.x, g = blockIdx.x * 256 + t;
    int v = (g < N_NODES) ? counts[g] : 0;
    s[t] = v;
    __syncthreads();
    #pragma unroll
    for (int off = 1; off < 256; off <<= 1) {
        int u = (t >= off) ? s[t - off] : 0;
        __syncthreads();
        s[t] += u;
        __syncthreads();
    }
    if (g < N_NODES) row_start[g] = s[t];
    if (t == 255) bsum[blockIdx.x] = s[255];
}

// ---------------------------------------------------------------------------
// CSR build, step 2b: exclusive scan of the 391 block sums (single block).
// ---------------------------------------------------------------------------
__global__ __launch_bounds__(512) void scan2(int* __restrict__ bsum, int nb)
{
    __shared__ int s[512];
    int t = threadIdx.x;
    int v = (t < nb) ? bsum[t] : 0;
    s[t] = v;
    __syncthreads();
    #pragma unroll
    for (int off = 1; off < 512; off <<= 1) {
        int u = (t >= off) ? s[t - off] : 0;
        __syncthreads();
        s[t] += u;
        __syncthreads();
    }
    if (t < nb) bsum[t] = s[t] - v;   // exclusive
}

// ---------------------------------------------------------------------------
// CSR build, step 2c: combine into global exclusive row_start; init cursors.
// ---------------------------------------------------------------------------
__global__ __launch_bounds__(256) void scan3(
    const int* __restrict__ counts, const int* __restrict__ bsum,
    int* __restrict__ row_start, int* __restrict__ next)
{
    int g = blockIdx.x * 256 + threadIdx.x;
    if (g < N_NODES) {
        int incl = row_start[g];                   // from scan1
        int rs = incl - counts[g] + bsum[blockIdx.x];
        row_start[g] = rs;
        next[g] = rs;
    }
    if (g == 0) row_start[N_NODES] = E_EDGES;
}

// ---------------------------------------------------------------------------
// CSR build, step 3: scatter {edge id, src id} into dst-sorted adjacency.
// ---------------------------------------------------------------------------
__global__ __launch_bounds__(256) void scatter_k(
    const int* __restrict__ dst, const int* __restrict__ src,
    int* __restrict__ next, int2* __restrict__ adj)
{
    int t = blockIdx.x * 256 + threadIdx.x;
    if (t < E_EDGES / 4) {
        ivec4 d = __builtin_nontemporal_load((const ivec4*)dst + t);
        ivec4 s = __builtin_nontemporal_load((const ivec4*)src + t);
        unsigned long long e0 = (unsigned long long)(4 * t);
        int p0 = atomicAdd(&next[d.x], 1);
        __builtin_nontemporal_store(
            (e0 + 0) | ((unsigned long long)(unsigned)s.x << 32),
            (unsigned long long*)&adj[p0]);
        int p1 = atomicAdd(&next[d.y], 1);
        __builtin_nontemporal_store(
            (e0 + 1) | ((unsigned long long)(unsigned)s.y << 32),
            (unsigned long long*)&adj[p1]);
        int p2 = atomicAdd(&next[d.z], 1);
        __builtin_nontemporal_store(
            (e0 + 2) | ((unsigned long long)(unsigned)s.z << 32),
            (unsigned long long*)&adj[p2]);
        int p3 = atomicAdd(&next[d.w], 1);
        __builtin_nontemporal_store(
            (e0 + 3) | ((unsigned long long)(unsigned)s.w << 32),
            (unsigned long long*)&adj[p3]);
    }
}

// ---------------------------------------------------------------------------
// Fused aggregation + MessageNorm, with an idempotent in-dispatch repeat
// loop (PROBE: reps>1 amplifies this dispatch into the rocprof top-5 so we
// finally see its counters; output identical for any reps>=1).
// ---------------------------------------------------------------------------
__global__ __launch_bounds__(256) void aggregate(
    const float* __restrict__ feats, const float* __restrict__ edge_h,
    const int2* __restrict__ adj, const int* __restrict__ row_start,
    const float* __restrict__ scale, float* __restrict__ x, int reps)
{
    int node = blockIdx.x * 4 + (threadIdx.x >> 6);
    int lane = threadIdx.x & 63;
    if (node >= N_NODES) return;
    int rs = row_start[node], re = row_start[node + 1];

    for (int r = 0; r < reps; r++) {
        float den = 0.f, hn = 0.f;
        for (int base = rs; base < re; base += 64) {
            int rem = min(64, re - base);
            // lanes >= rem hold (0,0): safe dummy (edge 0 / node 0)
            int2 ad = make_int2(0, 0);
            if (base + lane < re) {
                unsigned long long v = __builtin_nontemporal_load(
                    (const unsigned long long*)&adj[base + lane]);
                ad.x = (int)(unsigned)v;
                ad.y = (int)(unsigned)(v >> 32);
            }
            for (int j = 0; j < rem; j += 8) {
                #pragma unroll
                for (int u = 0; u < 8; u++) {
                    int jj = j + u;
                    int eid = __shfl(ad.x, jj);
                    int sid = __shfl(ad.y, jj);
                    float fv = feats[(size_t)sid * D_IN + lane];
                    float ev = __builtin_nontemporal_load(
                                   &edge_h[(size_t)eid * D_IN + lane]);
                    float m = fmaxf(fv + ev, 0.f) + EPS_GEN;
                    float ex = __expf(m);
                    bool ok = jj < rem;
                    den += ok ? ex : 0.f;
                    hn  += ok ? m * ex : 0.f;
                }
            }
        }

        float h = den > 0.f ? hn / den : 0.f;
        float f = feats[(size_t)node * D_IN + lane];
        float s1 = h * h, s2 = f * f;
        #pragma unroll
        for (int off = 32; off > 0; off >>= 1) {
            s1 += __shfl_xor(s1, off, 64);
            s2 += __shfl_xor(s2, off, 64);
        }
        float xv = f + (h / fmaxf(sqrtf(s1), NORM_EPS)) * sqrtf(s2) * scale[0];
        x[(size_t)node * D_IN + lane] = xv;
    }
}

// ---------------------------------------------------------------------------
// PROBE: replica of hist's memory behavior into scratch counts2, R reps in
// one dispatch. Output unused; side effects confined to scratch.
// ---------------------------------------------------------------------------
__global__ __launch_bounds__(256) void hist_probe(
    const int* __restrict__ dst, int* __restrict__ counts2, int R)
{
    int t = blockIdx.x * 256 + threadIdx.x;
    if (t < E_EDGES / 4) {
        ivec4 d = __builtin_nontemporal_load((const ivec4*)dst + t);
        for (int r = 0; r < R; r++) {
            atomicAdd(&counts2[d.x], 1);
            atomicAdd(&counts2[d.y], 1);
            atomicAdd(&counts2[d.z], 1);
            atomicAdd(&counts2[d.w], 1);
        }
    }
}

// ---------------------------------------------------------------------------
// PROBE: init next2 cursors from row_start (scratch copy for scatter_probe).
// ---------------------------------------------------------------------------
__global__ __launch_bounds__(256) void init_next2(
    const int* __restrict__ row_start, int* __restrict__ next2)
{
    int g = blockIdx.x * 256 + threadIdx.x;
    if (g < N_NODES) next2[g] = row_start[g];
}

// ---------------------------------------------------------------------------
// PROBE: replica of scatter's memory behavior into scratch next2/adj2,
// R reps in one dispatch. Cursor drift across reps is bounded by
// (R-1)*deg_max (~420) -> adj2 has 4096 entries of slack.
// ---------------------------------------------------------------------------
__global__ __launch_bounds__(256) void scatter_probe(
    const int* __restrict__ dst, const int* __restrict__ src,
    int* __restrict__ next2, int2* __restrict__ adj2, int R)
{
    int t = blockIdx.x * 256 + threadIdx.x;
    if (t < E_EDGES / 4) {
        ivec4 d = __builtin_nontemporal_load((const ivec4*)dst + t);
        ivec4 s = __builtin_nontemporal_load((const ivec4*)src + t);
        unsigned long long e0 = (unsigned long long)(4 * t);
        for (int r = 0; r < R; r++) {
            int p0 = atomicAdd(&next2[d.x], 1);
            __builtin_nontemporal_store(
                (e0 + 0) | ((unsigned long long)(unsigned)s.x << 32),
                (unsigned long long*)&adj2[p0]);
            int p1 = atomicAdd(&next2[d.y], 1);
            __builtin_nontemporal_store(
                (e0 + 1) | ((unsigned long long)(unsigned)s.y << 32),
                (unsigned long long*)&adj2[p1]);
            int p2 = atomicAdd(&next2[d.z], 1);
            __builtin_nontemporal_store(
                (e0 + 2) | ((unsigned long long)(unsigned)s.z << 32),
                (unsigned long long*)&adj2[p2]);
            int p3 = atomicAdd(&next2[d.w], 1);
            __builtin_nontemporal_store(
                (e0 + 3) | ((unsigned long long)(unsigned)s.w << 32),
                (unsigned long long*)&adj2[p3]);
        }
    }
}

// ---------------------------------------------------------------------------
// GEMM1: y1 = x[N,64] @ W1[64,128] + b1, fused BN batch-stat partials.
// ---------------------------------------------------------------------------
__global__ __launch_bounds__(256) void gemm1_stats(
    const float* __restrict__ x, const float* __restrict__ W1,
    const float* __restrict__ b1, float* __restrict__ y1,
    float* __restrict__ stats)
{
    __shared__ float wlds[D_IN * H_DIM];   // 32 KB
    __shared__ float ssum[H_DIM], ssq[H_DIM];
    int tid = threadIdx.x;
    {
        const float4* wg = (const float4*)W1;
        float4* wl = (float4*)wlds;
        #pragma unroll
        for (int i = 0; i < 8; i++) wl[tid + i * 256] = wg[tid + i * 256];
    }
    if (tid < H_DIM) { ssum[tid] = 0.f; ssq[tid] = 0.f; }
    __syncthreads();

    int rg = tid >> 5, cg = tid & 31;
    int r0 = blockIdx.x * 32 + rg * 4;
    int c0 = cg * 4;
    float acc[4][4];
    {
        float4 bb = *(const float4*)(b1 + c0);
        #pragma unroll
        for (int i = 0; i < 4; i++) {
            acc[i][0] = bb.x; acc[i][1] = bb.y; acc[i][2] = bb.z; acc[i][3] = bb.w;
        }
    }
    #pragma unroll 2
    for (int kc = 0; kc < D_IN; kc += 4) {
        float4 xr[4];
        #pragma unroll
        for (int i = 0; i < 4; i++) {
            int r = r0 + i;
            xr[i] = (r < N_NODES) ? *(const float4*)(x + (size_t)r * D_IN + kc)
                                  : make_float4(0.f, 0.f, 0.f, 0.f);
        }
        #pragma unroll
        for (int kk = 0; kk < 4; kk++) {
            float4 w4 = *(const float4*)&wlds[(kc + kk) * H_DIM + c0];
            #pragma unroll
            for (int i = 0; i < 4; i++) {
                float xv = ((const float*)&xr[i])[kk];
                acc[i][0] = fmaf(xv, w4.x, acc[i][0]);
                acc[i][1] = fmaf(xv, w4.y, acc[i][1]);
                acc[i][2] = fmaf(xv, w4.z, acc[i][2]);
                acc[i][3] = fmaf(xv, w4.w, acc[i][3]);
            }
        }
    }
    float cs[4] = {0.f, 0.f, 0.f, 0.f}, cq[4] = {0.f, 0.f, 0.f, 0.f};
    #pragma unroll
    for (int i = 0; i < 4; i++) {
        int r = r0 + i;
        if (r < N_NODES) {
            *(float4*)(y1 + (size_t)r * H_DIM + c0) =
                make_float4(acc[i][0], acc[i][1], acc[i][2], acc[i][3]);
            #pragma unroll
            for (int j = 0; j < 4; j++) {
                cs[j] += acc[i][j];
                cq[j] += acc[i][j] * acc[i][j];
            }
        }
    }
    #pragma unroll
    for (int j = 0; j < 4; j++) {
        atomicAdd(&ssum[c0 + j], cs[j]);
        atomicAdd(&ssq[c0 + j], cq[j]);
    }
    __syncthreads();
    if (tid < H_DIM) {
        unsafeAtomicAdd(&stats[tid], ssum[tid]);
        unsafeAtomicAdd(&stats[H_DIM + tid], ssq[tid]);
    }
}

// ---------------------------------------------------------------------------
// GEMM2: out = relu(BN(y1)) @ W2 + b2.
// ---------------------------------------------------------------------------
__global__ __launch_bounds__(256) void gemm2_bn(
    const float* __restrict__ y1, const float* __restrict__ W2,
    const float* __restrict__ b2, const float* __restrict__ stats,
    const float* __restrict__ gamma, const float* __restrict__ beta,
    float* __restrict__ out)
{
    __shared__ float wlds[H_DIM * OUT_DIM];   // 32 KB
    __shared__ float sc[H_DIM], sh[H_DIM];
    int tid = threadIdx.x;
    {
        const float4* wg = (const float4*)W2;
        float4* wl = (float4*)wlds;
        #pragma unroll
        for (int i = 0; i < 8; i++) wl[tid + i * 256] = wg[tid + i * 256];
    }
    if (tid < H_DIM) {
        float mean = stats[tid] * (1.f / N_NODES);
        float var  = stats[H_DIM + tid] * (1.f / N_NODES) - mean * mean;
        float rs   = rsqrtf(var + BN_EPS);
        float s    = gamma[tid] * rs;
        sc[tid] = s;
        sh[tid] = beta[tid] - mean * s;
    }
    __syncthreads();

    int rg = tid >> 4, cg = tid & 15;
    int r0 = blockIdx.x * 64 + rg * 4;
    int c0 = cg * 4;
    float acc[4][4];
    {
        float4 bb = *(const float4*)(b2 + c0);
        #pragma unroll
        for (int i = 0; i < 4; i++) {
            acc[i][0] = bb.x; acc[i][1] = bb.y; acc[i][2] = bb.z; acc[i][3] = bb.w;
        }
    }
    #pragma unroll 2
    for (int kc = 0; kc < H_DIM; kc += 4) {
        float4 sc4 = *(const float4*)&sc[kc];
        float4 sh4 = *(const float4*)&sh[kc];
        float4 yr[4];
        #pragma unroll
        for (int i = 0; i < 4; i++) {
            int r = r0 + i;
            if (r < N_NODES) {
                float4 v = *(const float4*)(y1 + (size_t)r * H_DIM + kc);
                v.x = fmaxf(fmaf(v.x, sc4.x, sh4.x), 0.f);
                v.y = fmaxf(fmaf(v.y, sc4.y, sh4.y), 0.f);
                v.z = fmaxf(fmaf(v.z, sc4.z, sh4.z), 0.f);
                v.w = fmaxf(fmaf(v.w, sc4.w, sh4.w), 0.f);
                yr[i] = v;
            } else {
                yr[i] = make_float4(0.f, 0.f, 0.f, 0.f);
            }
        }
        #pragma unroll
        for (int kk = 0; kk < 4; kk++) {
            float4 w4 = *(const float4*)&wlds[(kc + kk) * OUT_DIM + c0];
            #pragma unroll
            for (int i = 0; i < 4; i++) {
                float yv = ((const float*)&yr[i])[kk];
                acc[i][0] = fmaf(yv, w4.x, acc[i][0]);
                acc[i][1] = fmaf(yv, w4.y, acc[i][1]);
                acc[i][2] = fmaf(yv, w4.z, acc[i][2]);
                acc[i][3] = fmaf(yv, w4.w, acc[i][3]);
            }
        }
    }
    #pragma unroll
    for (int i = 0; i < 4; i++) {
        int r = r0 + i;
        if (r < N_NODES) {
            *(float4*)(out + (size_t)r * OUT_DIM + c0) =
                make_float4(acc[i][0], acc[i][1], acc[i][2], acc[i][3]);
        }
    }
}

// ---------------------------------------------------------------------------
// ATTRIBUTION ROUND 2: single real pipeline; aggregate amplified in-dispatch
// (reps=6, idempotent); hist/scatter replicated into scratch with R=8.
// Expect aggregate / hist_probe / scatter_probe rows in rocprof top-5 with
// their own counters. dur_us inflated this round by design.
// ---------------------------------------------------------------------------
extern "C" void kernel_launch(void* const* d_in, const int* in_sizes, int n_in,
                              void* d_out, int out_size, void* d_ws, size_t ws_size,
                              hipStream_t stream)
{
    const float* feats   = (const float*)d_in[0];
    const float* edge_h  = (const float*)d_in[1];
    const int*   src     = (const int*)d_in[2];
    const int*   dst     = (const int*)d_in[3];
    const float* W1      = (const float*)d_in[4];
    const float* b1      = (const float*)d_in[5];
    const float* gamma   = (const float*)d_in[6];
    const float* bn_beta = (const float*)d_in[7];
    const float* W2      = (const float*)d_in[8];
    const float* b2      = (const float*)d_in[9];
    const float* scale   = (const float*)d_in[10];
    float* out = (float*)d_out;

    const size_t ND = (size_t)N_NODES * D_IN;
    char* ws = (char*)d_ws;
    int*   counts    = (int*)ws;                          ws += (size_t)N_NODES * 4;
    float* stats     = (float*)ws;                        ws += 256 * 4;
    int*   bsum      = (int*)ws;                          ws += 512 * 4;
    int*   row_start = (int*)ws;                          ws += (size_t)(N_NODES + 1) * 4;
    int*   next      = (int*)ws;                          ws += (size_t)(N_NODES + 1) * 4;
    int2*  adj       = (int2*)ws;                         ws += (size_t)E_EDGES * 8;
    float* xbuf      = (float*)ws;                        ws += ND * 4;
    float* y1        = (float*)ws;                        ws += (size_t)N_NODES * H_DIM * 4;
    // probe scratch (never read; never touches pipeline buffers)
    int*   counts2   = (int*)ws;                          ws += (size_t)N_NODES * 4;
    int*   next2     = (int*)ws;                          ws += (size_t)N_NODES * 4;
    int2*  adj2      = (int2*)ws;

    const int NB = (N_NODES + 255) / 256;   // 391
    const int EB4 = (E_EDGES / 4 + 255) / 256;   // 1563

    // zero counts + stats in one memset (contiguous)
    hipMemsetAsync(counts, 0, (size_t)(N_NODES + 256) * 4, stream);

    hist_kernel<<<EB4, 256, 0, stream>>>(dst, counts);
    scan1<<<NB, 256, 0, stream>>>(counts, row_start, bsum);
    scan2<<<1, 512, 0, stream>>>(bsum, NB);
    scan3<<<NB, 256, 0, stream>>>(counts, bsum, row_start, next);
    scatter_k<<<EB4, 256, 0, stream>>>(dst, src, next, adj);
    aggregate<<<(N_NODES + 3) / 4, 256, 0, stream>>>(feats, edge_h, adj, row_start, scale, xbuf, AGG_REPS);
    gemm1_stats<<<(N_NODES + 31) / 32, 256, 0, stream>>>(xbuf, W1, b1, y1, stats);
    gemm2_bn<<<(N_NODES + 63) / 64, 256, 0, stream>>>(y1, W2, b2, stats, gamma, bn_beta, out);

    // --- probes (after the real pipeline; results unused) ---
    hist_probe<<<EB4, 256, 0, stream>>>(dst, counts2, PROBE_R);
    init_next2<<<NB, 256, 0, stream>>>(row_start, next2);
    scatter_probe<<<EB4, 256, 0, stream>>>(dst, src, next2, adj2, PROBE_R);
}

// Round 6
// 1128.580 us; speedup vs baseline: 2.8034x; 2.8034x over previous
//
#include <hip/hip_runtime.h>
#include <cstdint>

#define N_NODES 100000
#define E_EDGES 1600000
#define D_IN 64
#define H_DIM 128
#define OUT_DIM 64
#define EPS_GEN 1e-7f
#define BN_EPS 1e-5f
#define NORM_EPS 1e-12f

// Clang-native int vector: __builtin_nontemporal_load requires a real vector
// type (HIP's int4 is a class and is rejected).
typedef int ivec4 __attribute__((ext_vector_type(4)));

// ---------------------------------------------------------------------------
// CSR build, step 1: per-dst degree histogram. ivec4 = 4 edges/thread.
// ---------------------------------------------------------------------------
__global__ __launch_bounds__(256) void hist_kernel(
    const int* __restrict__ dst, int* __restrict__ counts)
{
    int t = blockIdx.x * 256 + threadIdx.x;
    if (t < E_EDGES / 4) {
        ivec4 d = __builtin_nontemporal_load((const ivec4*)dst + t);
        atomicAdd(&counts[d.x], 1);
        atomicAdd(&counts[d.y], 1);
        atomicAdd(&counts[d.z], 1);
        atomicAdd(&counts[d.w], 1);
    }
}

// ---------------------------------------------------------------------------
// CSR build, step 2a: per-block inclusive scan of counts (256/block).
// ---------------------------------------------------------------------------
__global__ __launch_bounds__(256) void scan1(
    const int* __restrict__ counts, int* __restrict__ row_start,
    int* __restrict__ bsum)
{
    __shared__ int s[256];
    int t = threadIdx.x, g = blockIdx.x * 256 + t;
    int v = (g < N_NODES) ? counts[g] : 0;
    s[t] = v;
    __syncthreads();
    #pragma unroll
    for (int off = 1; off < 256; off <<= 1) {
        int u = (t >= off) ? s[t - off] : 0;
        __syncthreads();
        s[t] += u;
        __syncthreads();
    }
    if (g < N_NODES) row_start[g] = s[t];
    if (t == 255) bsum[blockIdx.x] = s[255];
}

// ---------------------------------------------------------------------------
// CSR build, step 2b: exclusive scan of the 391 block sums (single block).
// ---------------------------------------------------------------------------
__global__ __launch_bounds__(512) void scan2(int* __restrict__ bsum, int nb)
{
    __shared__ int s[512];
    int t = threadIdx.x;
    int v = (t < nb) ? bsum[t] : 0;
    s[t] = v;
    __syncthreads();
    #pragma unroll
    for (int off = 1; off < 512; off <<= 1) {
        int u = (t >= off) ? s[t - off] : 0;
        __syncthreads();
        s[t] += u;
        __syncthreads();
    }
    if (t < nb) bsum[t] = s[t] - v;   // exclusive
}

// ---------------------------------------------------------------------------
// CSR build, step 2c: combine into global exclusive row_start; init cursors.
// ---------------------------------------------------------------------------
__global__ __launch_bounds__(256) void scan3(
    const int* __restrict__ counts, const int* __restrict__ bsum,
    int* __restrict__ row_start, int* __restrict__ next)
{
    int g = blockIdx.x * 256 + threadIdx.x;
    if (g < N_NODES) {
        int incl = row_start[g];                   // from scan1
        int rs = incl - counts[g] + bsum[blockIdx.x];
        row_start[g] = rs;
        next[g] = rs;
    }
    if (g == 0) row_start[N_NODES] = E_EDGES;
}

// ===========================================================================
// NEW PATH (needs ~488MB workspace): scatter the computed MESSAGE ROW
// m = relu(feats[src]+edge_h)+eps to its dst-sorted slot.
//  - edge_h read is fully SEQUENTIAL (was the 410MB random-read in aggregate)
//  - mS writes are 256B rows = 4 full lines (vs 8B adj stores that cost a
//    64B line each: measured 8.3x write amplification, 852MB for 102MB)
//  - downstream aggregate becomes a pure sequential streaming reduce
// ===========================================================================

// One wave handles 8 consecutive edges: 16 loads in flight (8 seq edge_h rows
// + 8 cached feats rows), 8 full-line row stores, 8 atomics (one per edge).
__global__ __launch_bounds__(256) void scatter_m(
    const int* __restrict__ dst, const int* __restrict__ src,
    const float* __restrict__ feats, const float* __restrict__ edge_h,
    int* __restrict__ next, float* __restrict__ mS)
{
    int wid  = blockIdx.x * 4 + (threadIdx.x >> 6);   // global wave id
    int lane = threadIdx.x & 63;
    int e0 = wid * 8;                                  // exact: grid = E/32
    // lanes 0..7 fetch ids and claim slots
    int d_l = 0, s_l = 0, p_l = 0;
    if (lane < 8) {
        d_l = dst[e0 + lane];
        s_l = src[e0 + lane];
        p_l = atomicAdd(&next[d_l], 1);
    }
    float ev[8], fv[8];
    int   pu[8];
    #pragma unroll
    for (int u = 0; u < 8; u++) {
        pu[u] = __shfl(p_l, u);
        int su = __shfl(s_l, u);
        ev[u] = __builtin_nontemporal_load(
                    &edge_h[(size_t)(e0 + u) * D_IN + lane]);
        fv[u] = feats[(size_t)su * D_IN + lane];
    }
    #pragma unroll
    for (int u = 0; u < 8; u++) {
        float m = fmaxf(fv[u] + ev[u], 0.f) + EPS_GEN;
        __builtin_nontemporal_store(m, &mS[(size_t)pu[u] * D_IN + lane]);
    }
}

// One wave per node: sequential streaming reduce of its m-rows, then
// MessageNorm. den = sum exp(m), hn = sum m*exp(m); h = hn/den.
__global__ __launch_bounds__(256) void aggregate_seq(
    const float* __restrict__ feats, const float* __restrict__ mS,
    const int* __restrict__ row_start, const float* __restrict__ scale,
    float* __restrict__ x)
{
    int node = blockIdx.x * 4 + (threadIdx.x >> 6);
    int lane = threadIdx.x & 63;
    if (node >= N_NODES) return;
    int rs = row_start[node], re = row_start[node + 1];
    float den = 0.f, hn = 0.f;

    for (int base = rs; base < re; base += 8) {
        #pragma unroll
        for (int u = 0; u < 8; u++) {
            bool ok = base + u < re;
            float mv = ok ? __builtin_nontemporal_load(
                               &mS[(size_t)(base + u) * D_IN + lane]) : 0.f;
            float ex = __expf(mv);
            den += ok ? ex : 0.f;
            hn  += ok ? mv * ex : 0.f;
        }
    }

    float h = den > 0.f ? hn / den : 0.f;
    float f = feats[(size_t)node * D_IN + lane];
    float s1 = h * h, s2 = f * f;
    #pragma unroll
    for (int off = 32; off > 0; off >>= 1) {
        s1 += __shfl_xor(s1, off, 64);
        s2 += __shfl_xor(s2, off, 64);
    }
    float xv = f + (h / fmaxf(sqrtf(s1), NORM_EPS)) * sqrtf(s2) * scale[0];
    x[(size_t)node * D_IN + lane] = xv;
}

// ===========================================================================
// FALLBACK PATH (round-3 pipeline, used when workspace < ~488MB)
// ===========================================================================
__global__ __launch_bounds__(256) void scatter_k(
    const int* __restrict__ dst, const int* __restrict__ src,
    int* __restrict__ next, int2* __restrict__ adj)
{
    int t = blockIdx.x * 256 + threadIdx.x;
    if (t < E_EDGES / 4) {
        ivec4 d = __builtin_nontemporal_load((const ivec4*)dst + t);
        ivec4 s = __builtin_nontemporal_load((const ivec4*)src + t);
        unsigned long long e0 = (unsigned long long)(4 * t);
        int p0 = atomicAdd(&next[d.x], 1);
        __builtin_nontemporal_store(
            (e0 + 0) | ((unsigned long long)(unsigned)s.x << 32),
            (unsigned long long*)&adj[p0]);
        int p1 = atomicAdd(&next[d.y], 1);
        __builtin_nontemporal_store(
            (e0 + 1) | ((unsigned long long)(unsigned)s.y << 32),
            (unsigned long long*)&adj[p1]);
        int p2 = atomicAdd(&next[d.z], 1);
        __builtin_nontemporal_store(
            (e0 + 2) | ((unsigned long long)(unsigned)s.z << 32),
            (unsigned long long*)&adj[p2]);
        int p3 = atomicAdd(&next[d.w], 1);
        __builtin_nontemporal_store(
            (e0 + 3) | ((unsigned long long)(unsigned)s.w << 32),
            (unsigned long long*)&adj[p3]);
    }
}

__global__ __launch_bounds__(256) void aggregate(
    const float* __restrict__ feats, const float* __restrict__ edge_h,
    const int2* __restrict__ adj, const int* __restrict__ row_start,
    const float* __restrict__ scale, float* __restrict__ x)
{
    int node = blockIdx.x * 4 + (threadIdx.x >> 6);
    int lane = threadIdx.x & 63;
    if (node >= N_NODES) return;
    int rs = row_start[node], re = row_start[node + 1];
    float den = 0.f, hn = 0.f;

    for (int base = rs; base < re; base += 64) {
        int rem = min(64, re - base);
        int2 ad = make_int2(0, 0);
        if (base + lane < re) {
            unsigned long long v = __builtin_nontemporal_load(
                (const unsigned long long*)&adj[base + lane]);
            ad.x = (int)(unsigned)v;
            ad.y = (int)(unsigned)(v >> 32);
        }
        for (int j = 0; j < rem; j += 8) {
            #pragma unroll
            for (int u = 0; u < 8; u++) {
                int jj = j + u;
                int eid = __shfl(ad.x, jj);
                int sid = __shfl(ad.y, jj);
                float fv = feats[(size_t)sid * D_IN + lane];
                float ev = __builtin_nontemporal_load(
                               &edge_h[(size_t)eid * D_IN + lane]);
                float m = fmaxf(fv + ev, 0.f) + EPS_GEN;
                float ex = __expf(m);
                bool ok = jj < rem;
                den += ok ? ex : 0.f;
                hn  += ok ? m * ex : 0.f;
            }
        }
    }

    float h = den > 0.f ? hn / den : 0.f;
    float f = feats[(size_t)node * D_IN + lane];
    float s1 = h * h, s2 = f * f;
    #pragma unroll
    for (int off = 32; off > 0; off >>= 1) {
        s1 += __shfl_xor(s1, off, 64);
        s2 += __shfl_xor(s2, off, 64);
    }
    float xv = f + (h / fmaxf(sqrtf(s1), NORM_EPS)) * sqrtf(s2) * scale[0];
    x[(size_t)node * D_IN + lane] = xv;
}

// ---------------------------------------------------------------------------
// GEMM1: y1 = x[N,64] @ W1[64,128] + b1, fused BN batch-stat partials.
// ---------------------------------------------------------------------------
__global__ __launch_bounds__(256) void gemm1_stats(
    const float* __restrict__ x, const float* __restrict__ W1,
    const float* __restrict__ b1, float* __restrict__ y1,
    float* __restrict__ stats)
{
    __shared__ float wlds[D_IN * H_DIM];   // 32 KB
    __shared__ float ssum[H_DIM], ssq[H_DIM];
    int tid = threadIdx.x;
    {
        const float4* wg = (const float4*)W1;
        float4* wl = (float4*)wlds;
        #pragma unroll
        for (int i = 0; i < 8; i++) wl[tid + i * 256] = wg[tid + i * 256];
    }
    if (tid < H_DIM) { ssum[tid] = 0.f; ssq[tid] = 0.f; }
    __syncthreads();

    int rg = tid >> 5, cg = tid & 31;
    int r0 = blockIdx.x * 32 + rg * 4;
    int c0 = cg * 4;
    float acc[4][4];
    {
        float4 bb = *(const float4*)(b1 + c0);
        #pragma unroll
        for (int i = 0; i < 4; i++) {
            acc[i][0] = bb.x; acc[i][1] = bb.y; acc[i][2] = bb.z; acc[i][3] = bb.w;
        }
    }
    #pragma unroll 2
    for (int kc = 0; kc < D_IN; kc += 4) {
        float4 xr[4];
        #pragma unroll
        for (int i = 0; i < 4; i++) {
            int r = r0 + i;
            xr[i] = (r < N_NODES) ? *(const float4*)(x + (size_t)r * D_IN + kc)
                                  : make_float4(0.f, 0.f, 0.f, 0.f);
        }
        #pragma unroll
        for (int kk = 0; kk < 4; kk++) {
            float4 w4 = *(const float4*)&wlds[(kc + kk) * H_DIM + c0];
            #pragma unroll
            for (int i = 0; i < 4; i++) {
                float xv = ((const float*)&xr[i])[kk];
                acc[i][0] = fmaf(xv, w4.x, acc[i][0]);
                acc[i][1] = fmaf(xv, w4.y, acc[i][1]);
                acc[i][2] = fmaf(xv, w4.z, acc[i][2]);
                acc[i][3] = fmaf(xv, w4.w, acc[i][3]);
            }
        }
    }
    float cs[4] = {0.f, 0.f, 0.f, 0.f}, cq[4] = {0.f, 0.f, 0.f, 0.f};
    #pragma unroll
    for (int i = 0; i < 4; i++) {
        int r = r0 + i;
        if (r < N_NODES) {
            *(float4*)(y1 + (size_t)r * H_DIM + c0) =
                make_float4(acc[i][0], acc[i][1], acc[i][2], acc[i][3]);
            #pragma unroll
            for (int j = 0; j < 4; j++) {
                cs[j] += acc[i][j];
                cq[j] += acc[i][j] * acc[i][j];
            }
        }
    }
    #pragma unroll
    for (int j = 0; j < 4; j++) {
        atomicAdd(&ssum[c0 + j], cs[j]);
        atomicAdd(&ssq[c0 + j], cq[j]);
    }
    __syncthreads();
    if (tid < H_DIM) {
        unsafeAtomicAdd(&stats[tid], ssum[tid]);
        unsafeAtomicAdd(&stats[H_DIM + tid], ssq[tid]);
    }
}

// ---------------------------------------------------------------------------
// GEMM2: out = relu(BN(y1)) @ W2 + b2.
// ---------------------------------------------------------------------------
__global__ __launch_bounds__(256) void gemm2_bn(
    const float* __restrict__ y1, const float* __restrict__ W2,
    const float* __restrict__ b2, const float* __restrict__ stats,
    const float* __restrict__ gamma, const float* __restrict__ beta,
    float* __restrict__ out)
{
    __shared__ float wlds[H_DIM * OUT_DIM];   // 32 KB
    __shared__ float sc[H_DIM], sh[H_DIM];
    int tid = threadIdx.x;
    {
        const float4* wg = (const float4*)W2;
        float4* wl = (float4*)wlds;
        #pragma unroll
        for (int i = 0; i < 8; i++) wl[tid + i * 256] = wg[tid + i * 256];
    }
    if (tid < H_DIM) {
        float mean = stats[tid] * (1.f / N_NODES);
        float var  = stats[H_DIM + tid] * (1.f / N_NODES) - mean * mean;
        float rs   = rsqrtf(var + BN_EPS);
        float s    = gamma[tid] * rs;
        sc[tid] = s;
        sh[tid] = beta[tid] - mean * s;
    }
    __syncthreads();

    int rg = tid >> 4, cg = tid & 15;
    int r0 = blockIdx.x * 64 + rg * 4;
    int c0 = cg * 4;
    float acc[4][4];
    {
        float4 bb = *(const float4*)(b2 + c0);
        #pragma unroll
        for (int i = 0; i < 4; i++) {
            acc[i][0] = bb.x; acc[i][1] = bb.y; acc[i][2] = bb.z; acc[i][3] = bb.w;
        }
    }
    #pragma unroll 2
    for (int kc = 0; kc < H_DIM; kc += 4) {
        float4 sc4 = *(const float4*)&sc[kc];
        float4 sh4 = *(const float4*)&sh[kc];
        float4 yr[4];
        #pragma unroll
        for (int i = 0; i < 4; i++) {
            int r = r0 + i;
            if (r < N_NODES) {
                float4 v = *(const float4*)(y1 + (size_t)r * H_DIM + kc);
                v.x = fmaxf(fmaf(v.x, sc4.x, sh4.x), 0.f);
                v.y = fmaxf(fmaf(v.y, sc4.y, sh4.y), 0.f);
                v.z = fmaxf(fmaf(v.z, sc4.z, sh4.z), 0.f);
                v.w = fmaxf(fmaf(v.w, sc4.w, sh4.w), 0.f);
                yr[i] = v;
            } else {
                yr[i] = make_float4(0.f, 0.f, 0.f, 0.f);
            }
        }
        #pragma unroll
        for (int kk = 0; kk < 4; kk++) {
            float4 w4 = *(const float4*)&wlds[(kc + kk) * OUT_DIM + c0];
            #pragma unroll
            for (int i = 0; i < 4; i++) {
                float yv = ((const float*)&yr[i])[kk];
                acc[i][0] = fmaf(yv, w4.x, acc[i][0]);
                acc[i][1] = fmaf(yv, w4.y, acc[i][1]);
                acc[i][2] = fmaf(yv, w4.z, acc[i][2]);
                acc[i][3] = fmaf(yv, w4.w, acc[i][3]);
            }
        }
    }
    #pragma unroll
    for (int i = 0; i < 4; i++) {
        int r = r0 + i;
        if (r < N_NODES) {
            *(float4*)(out + (size_t)r * OUT_DIM + c0) =
                make_float4(acc[i][0], acc[i][1], acc[i][2], acc[i][3]);
        }
    }
}

// ---------------------------------------------------------------------------
// Launcher. New path workspace:
//   counts[N] + stats[256]  (zeroed together)
//   bsum[512], row_start[N+1], next[N+1]
//   mS   float[E*64]   (409.6 MB)  <- message rows, dst-sorted
//   x    float[N*64], y1 float[N*128]
// Total ~488MB; if ws_size is smaller, fall back to the round-3 pipeline
// (adj int2[E] instead of mS).
// ---------------------------------------------------------------------------
extern "C" void kernel_launch(void* const* d_in, const int* in_sizes, int n_in,
                              void* d_out, int out_size, void* d_ws, size_t ws_size,
                              hipStream_t stream)
{
    const float* feats   = (const float*)d_in[0];
    const float* edge_h  = (const float*)d_in[1];
    const int*   src     = (const int*)d_in[2];
    const int*   dst     = (const int*)d_in[3];
    const float* W1      = (const float*)d_in[4];
    const float* b1      = (const float*)d_in[5];
    const float* gamma   = (const float*)d_in[6];
    const float* bn_beta = (const float*)d_in[7];
    const float* W2      = (const float*)d_in[8];
    const float* b2      = (const float*)d_in[9];
    const float* scale   = (const float*)d_in[10];
    float* out = (float*)d_out;

    const size_t ND = (size_t)N_NODES * D_IN;
    const size_t head = (size_t)N_NODES * 4 + 256 * 4 + 512 * 4
                      + (size_t)(N_NODES + 1) * 4 * 2;
    const size_t need_new = head + (size_t)E_EDGES * D_IN * 4
                          + ND * 4 + (size_t)N_NODES * H_DIM * 4;

    char* ws = (char*)d_ws;
    int*   counts    = (int*)ws;                          ws += (size_t)N_NODES * 4;
    float* stats     = (float*)ws;                        ws += 256 * 4;
    int*   bsum      = (int*)ws;                          ws += 512 * 4;
    int*   row_start = (int*)ws;                          ws += (size_t)(N_NODES + 1) * 4;
    int*   next      = (int*)ws;                          ws += (size_t)(N_NODES + 1) * 4;

    const int NB  = (N_NODES + 255) / 256;       // 391
    const int EB4 = (E_EDGES / 4 + 255) / 256;   // 1563

    // zero counts + stats in one memset (contiguous)
    hipMemsetAsync(counts, 0, (size_t)(N_NODES + 256) * 4, stream);

    hist_kernel<<<EB4, 256, 0, stream>>>(dst, counts);
    scan1<<<NB, 256, 0, stream>>>(counts, row_start, bsum);
    scan2<<<1, 512, 0, stream>>>(bsum, NB);
    scan3<<<NB, 256, 0, stream>>>(counts, bsum, row_start, next);

    if (ws_size >= need_new) {
        // ---- NEW PATH: message-row scatter + sequential reduce ----
        float* mS   = (float*)ws;                         ws += (size_t)E_EDGES * D_IN * 4;
        float* xbuf = (float*)ws;                         ws += ND * 4;
        float* y1   = (float*)ws;

        scatter_m<<<E_EDGES / 32, 256, 0, stream>>>(dst, src, feats, edge_h, next, mS);
        aggregate_seq<<<(N_NODES + 3) / 4, 256, 0, stream>>>(feats, mS, row_start, scale, xbuf);
        gemm1_stats<<<(N_NODES + 31) / 32, 256, 0, stream>>>(xbuf, W1, b1, y1, stats);
        gemm2_bn<<<(N_NODES + 63) / 64, 256, 0, stream>>>(y1, W2, b2, stats, gamma, bn_beta, out);
    } else {
        // ---- FALLBACK: round-3 pipeline ----
        int2*  adj  = (int2*)ws;                          ws += (size_t)E_EDGES * 8;
        float* xbuf = (float*)ws;                         ws += ND * 4;
        float* y1   = (float*)ws;

        scatter_k<<<EB4, 256, 0, stream>>>(dst, src, next, adj);
        aggregate<<<(N_NODES + 3) / 4, 256, 0, stream>>>(feats, edge_h, adj, row_start, scale, xbuf);
        gemm1_stats<<<(N_NODES + 31) / 32, 256, 0, stream>>>(xbuf, W1, b1, y1, stats);
        gemm2_bn<<<(N_NODES + 63) / 64, 256, 0, stream>>>(y1, W2, b2, stats, gamma, bn_beta, out);
    }
}